// Round 7
// baseline (229.920 us; speedup 1.0000x reference)
//
#include <hip/hip_runtime.h>

typedef unsigned short u16;
typedef unsigned int   u32;

#define PP 32768          // H*W*T
#define CC 64

__device__ __forceinline__ u16 f2b(float f) {
    u32 u; __builtin_memcpy(&u, &f, 4);
    u32 r = (u + 0x7FFFu + ((u >> 16) & 1u)) >> 16;
    return (u16)r;
}
__device__ __forceinline__ void unpack2(u32 v, float& lo, float& hi) {
    u32 a = v << 16; u32 b = v & 0xFFFF0000u;
    __builtin_memcpy(&lo, &a, 4); __builtin_memcpy(&hi, &b, 4);
}
__device__ __forceinline__ u32 pack2(float lo, float hi) {
    return (u32)f2b(lo) | ((u32)f2b(hi) << 16);
}

// ---------------- K1: prep = style-dot + wnorm + S zero-init ---------------
// grid 1024 = b*256 + o; 64 threads. Coalesced lw reads, partials in LDS.
__global__ __launch_bounds__(64) void k_prep(
        const float* __restrict__ style, const float* __restrict__ qkv_lw,
        const float* __restrict__ qkv_lb, const float* __restrict__ proj_lw,
        const float* __restrict__ proj_lb, const float* __restrict__ qkv_w,
        const float* __restrict__ proj_w, float* __restrict__ wqkT,
        float* __restrict__ wvT, float* __restrict__ wpT, float* __restrict__ S) {
    int id = blockIdx.x, b = id >> 8, o = id & 255, t = threadIdx.x;
    if (t < 32) S[(size_t)id * 32 + t] = 0.f;      // 1024*32 = |S| exactly
    const float* lw  = (o < 192) ? qkv_lw : proj_lw;
    const float* lbp = (o < 192) ? qkv_lb : proj_lb;
    __shared__ float part[64][65];                  // pad 65: conflict-free
    const float* st = style + b * 512 + t * 8;      // per-thread style slice
    float4 s0 = *(const float4*)st, s1 = *(const float4*)(st + 4);
    float sr[8] = {s0.x, s0.y, s0.z, s0.w, s1.x, s1.y, s1.z, s1.w};
    for (int i = 0; i < 64; ++i) {                  // coalesced 2KB row reads
        const float* wr = lw + (size_t)i * 512 + t * 8;
        float4 wa = *(const float4*)wr, wb2 = *(const float4*)(wr + 4);
        float p = wa.x*sr[0] + wa.y*sr[1] + wa.z*sr[2] + wa.w*sr[3]
                + wb2.x*sr[4] + wb2.y*sr[5] + wb2.z*sr[6] + wb2.w*sr[7];
        part[i][t] = p;
    }
    __syncthreads();
    float acc = 0.f;                                // s for channel t
    #pragma unroll 8
    for (int j = 0; j < 64; ++j) acc += part[t][j];
    float s_t = acc + lbp[t];
    float wv = ((o < 192) ? qkv_w[o * 64 + t] : proj_w[(o - 192) * 64 + t]) * s_t;
    float sq = wv * wv;
    #pragma unroll
    for (int off = 32; off > 0; off >>= 1) sq += __shfl_xor(sq, off, 64);
    float val = wv * rsqrtf(sq + 1e-8f);
    if (o < 128)      wqkT[((size_t)b * 64 + t) * 128 + o]        = val;
    else if (o < 192) wvT [((size_t)b * 64 + t) * 64 + (o - 128)] = val;
    else              wpT [((size_t)b * 64 + t) * 64 + (o - 192)] = val;
}

// ---------------- K2: fused q,k recompute + scores, 2 heads/block ----------
// grid 1024 = b(4) x np(4) x chunk(64 of 512p); 64 KB LDS -> 2 blocks/CU.
__global__ __launch_bounds__(256) void k_fscores(
        const float* __restrict__ x, const float* __restrict__ wqkT,
        const float* __restrict__ qnp, const float* __restrict__ qbp,
        const float* __restrict__ qnoise, float* __restrict__ S) {
    int bidx = blockIdx.x;
    int b = bidx >> 8, np = (bidx >> 6) & 3, chunk = bidx & 63;
    int n0 = np * 2;
    int tid = threadIdx.x;
    __shared__ float q_lds[16 * 512];   // [c16][p512] fp32, 32 KB
    __shared__ float k_lds[16 * 512];
    float qa[16][2], ka[16][2];
    #pragma unroll
    for (int c = 0; c < 16; ++c) {
        qa[c][0] = 0.f; qa[c][1] = 0.f; ka[c][0] = 0.f; ka[c][1] = 0.f;
    }
    const float* xb = x + (size_t)b * CC * PP + chunk * 512 + tid * 2;
    const float* wb = wqkT + (size_t)b * 8192 + n0 * 8;
    #pragma unroll 2
    for (int e = 0; e < 64; ++e) {
        float2 xv = *(const float2*)(xb + (size_t)e * PP);
        const float* wr = wb + e * 128;            // wave-uniform -> s_load
        #pragma unroll
        for (int c = 0; c < 16; ++c) {
            float wq_ = wr[c], wk_ = wr[64 + c];
            qa[c][0] = fmaf(wq_, xv.x, qa[c][0]);
            qa[c][1] = fmaf(wq_, xv.y, qa[c][1]);
            ka[c][0] = fmaf(wk_, xv.x, ka[c][0]);
            ka[c][1] = fmaf(wk_, xv.y, ka[c][1]);
        }
    }
    {
        float2 nz = *(const float2*)(qnoise + (size_t)b * PP + chunk * 512 + tid * 2);
        #pragma unroll
        for (int c = 0; c < 16; ++c) {
            float qn = qnp[n0 * 8 + c],      qb_ = qbp[n0 * 8 + c];
            float kn = qnp[64 + n0 * 8 + c], kb_ = qbp[64 + n0 * 8 + c];
            float2 qo = make_float2(qa[c][0] + qn * nz.x + qb_, qa[c][1] + qn * nz.y + qb_);
            float2 ko = make_float2(ka[c][0] + kn * nz.x + kb_, ka[c][1] + kn * nz.y + kb_);
            *(float2*)&q_lds[c * 512 + tid * 2] = qo;
            *(float2*)&k_lds[c * 512 + tid * 2] = ko;
        }
    }
    __syncthreads();
    int wave = tid >> 6, lane = tid & 63;
    int hsel = wave >> 1, eh = wave & 1;           // head-local, e-half
    int ig = lane >> 3, jg = lane & 7;
    float acc[16];
    #pragma unroll
    for (int q = 0; q < 16; ++q) acc[q] = 0.f;
    #pragma unroll 4
    for (int i = 0; i < 64; ++i) {
        int e = eh * 64 + i, c = e >> 4, hl = e & 15;
        float4 qv = *(const float4*)&q_lds[(hsel * 8 + c) * 512 + hl * 32 + ig * 4];
        float4 kv = *(const float4*)&k_lds[(hsel * 8 + c) * 512 + hl * 32 + jg * 4];
        float qa4[4] = {qv.x, qv.y, qv.z, qv.w};
        float ka4[4] = {kv.x, kv.y, kv.z, kv.w};
        #pragma unroll
        for (int ii = 0; ii < 4; ++ii)
            #pragma unroll
            for (int jj = 0; jj < 4; ++jj)
                acc[ii * 4 + jj] = fmaf(qa4[ii], ka4[jj], acc[ii * 4 + jj]);
    }
    __syncthreads();                   // q_lds dead -> reduction scratch
    #pragma unroll
    for (int t = 0; t < 16; ++t) q_lds[(wave * 16 + t) * 64 + lane] = acc[t];
    __syncthreads();
    if ((wave & 1) == 0) {             // waves 0,2 reduce + atomic per head
        float* Sb = S + ((size_t)b * 8 + n0 + hsel) * 1024;
        #pragma unroll
        for (int t = 0; t < 16; ++t) {
            float s2 = q_lds[(wave * 16 + t) * 64 + lane]
                     + q_lds[((wave + 1) * 16 + t) * 64 + lane];
            int ii = t >> 2, jj = t & 3;
            atomicAdd(&Sb[(ig * 4 + ii) * 32 + jg * 4 + jj], s2);
        }
    }
}

// ---------------- K3: softmax + v recompute + PV + proj --------------------
// grid 1024 = b x hwblk4; 256 thr; LDS 72.7 KB -> 2 blocks/CU.
__global__ __launch_bounds__(256) void k_out(
        const float* __restrict__ x, const float* __restrict__ wvT,
        const float* __restrict__ qnp, const float* __restrict__ qbp,
        const float* __restrict__ qnoise, const float* __restrict__ Sg,
        const float* __restrict__ wpT, const float* __restrict__ pnp,
        const float* __restrict__ pbp, const float* __restrict__ pnoise,
        float* __restrict__ out) {
    int bidx = blockIdx.x;
    int b = bidx >> 8, hw0 = (bidx & 255) * 4;
    int tid = threadIdx.x;
    __shared__ u32   P32s[8 * 576];     // [h][t*18 + jp] packed bf16 pairs
    __shared__ float uni[9216];         // ph1: xs[e][hwl*36+t]; ph2/3: As[i*132+hwl*33+t]
    __shared__ u32   v32s[64 * 68];     // [ich][hwl*17 + t/2] packed bf16 pairs
    // ---- fused softmax: thread = score row (n = tid>>5, i = tid&31) ----
    {
        int n = tid >> 5, i2 = tid & 31;
        const float* Srow = Sg + ((size_t)b * 8 + n) * 1024 + i2 * 32;
        float v[32];
        #pragma unroll
        for (int j4 = 0; j4 < 8; ++j4) {
            float4 s4 = *(const float4*)(Srow + j4 * 4);
            v[j4 * 4] = s4.x; v[j4 * 4 + 1] = s4.y;
            v[j4 * 4 + 2] = s4.z; v[j4 * 4 + 3] = s4.w;
        }
        float slope = exp2f(-(float)(n + 1));
        float m = -3e38f;
        #pragma unroll
        for (int j = 0; j < 32; ++j) {
            float val = v[j] * 0.011048543456039806f - slope * fabsf((float)(i2 - j));
            if (j <= i2) val = -1e18f;             // tril incl. diag masked
            v[j] = val; m = fmaxf(m, val);
        }
        float ssum = 0.f;
        #pragma unroll
        for (int j = 0; j < 32; ++j) { float e2 = expf(v[j] - m); v[j] = e2; ssum += e2; }
        float r = 1.f / ssum;
        #pragma unroll
        for (int jp = 0; jp < 16; ++jp)
            P32s[n * 576 + i2 * 18 + jp] = pack2(v[2 * jp] * r, v[2 * jp + 1] * r);
    }
    // ---- stage x: uni[e*144 + hwl*36 + t] ----
    const float* xb = x + (size_t)b * CC * PP + (size_t)hw0 * 32;
    #pragma unroll
    for (int r4 = 0; r4 < 8; ++r4) {
        int idx = r4 * 256 + tid;             // 0..2047 float4s
        int e = idx >> 5, rem = idx & 31, hwl = rem >> 3, tq = rem & 7;
        float4 xv = *(const float4*)(xb + (size_t)e * PP + rem * 4);
        *(float4*)&uni[e * 144 + hwl * 36 + tq * 4] = xv;
    }
    __syncthreads();
    // ---- phase 1: v = W x (4 vch x 8 t per thread) -> bf16 LDS ----
    {
        int ig = tid >> 4, r = tid & 15, hwl = r >> 2, th = r & 3, t0 = th * 8;
        float acc[4][8];
        #pragma unroll
        for (int ii = 0; ii < 4; ++ii)
            #pragma unroll
            for (int j = 0; j < 8; ++j) acc[ii][j] = 0.f;
        const float* wvb = wvT + (size_t)b * 4096 + ig * 4;
        #pragma unroll 2
        for (int e = 0; e < 64; ++e) {
            float4 w4 = *(const float4*)(wvb + e * 64);
            float wr[4] = {w4.x, w4.y, w4.z, w4.w};
            const float* xp = &uni[e * 144 + hwl * 36 + t0];
            float4 xa = *(const float4*)xp;
            float4 xc = *(const float4*)(xp + 4);
            float x8[8] = {xa.x, xa.y, xa.z, xa.w, xc.x, xc.y, xc.z, xc.w};
            #pragma unroll
            for (int ii = 0; ii < 4; ++ii)
                #pragma unroll
                for (int j = 0; j < 8; ++j)
                    acc[ii][j] = fmaf(wr[ii], x8[j], acc[ii][j]);
        }
        float4 np4 = *(const float4*)(qnp + 128 + ig * 4);
        float4 bp4 = *(const float4*)(qbp + 128 + ig * 4);
        float npr[4] = {np4.x, np4.y, np4.z, np4.w};
        float bpr[4] = {bp4.x, bp4.y, bp4.z, bp4.w};
        const float* nzp = qnoise + (size_t)b * PP + (size_t)(hw0 + hwl) * 32 + t0;
        float4 na = *(const float4*)nzp;
        float4 nc = *(const float4*)(nzp + 4);
        float nz[8] = {na.x, na.y, na.z, na.w, nc.x, nc.y, nc.z, nc.w};
        #pragma unroll
        for (int ii = 0; ii < 4; ++ii) {
            int ich = ig * 4 + ii;
            #pragma unroll
            for (int q = 0; q < 4; ++q) {
                float y0 = acc[ii][2*q]   + npr[ii] * nz[2*q]   + bpr[ii];
                float y1 = acc[ii][2*q+1] + npr[ii] * nz[2*q+1] + bpr[ii];
                v32s[ich * 68 + hwl * 17 + th * 4 + q] = pack2(y0, y1);
            }
        }
    }
    __syncthreads();   // v32s complete; uni (xs) dead -> becomes As
    // ---- phase 2: A[ich][hwl][t] = sum_j P[h][t][j] v[ich][hwl][j] ----
    {
        int p2 = tid >> 3, r3 = tid & 7, hwl2 = r3 >> 1, ts = (r3 & 1) * 16;
        int h = p2 >> 2;
        float vj[2][32];
        #pragma unroll
        for (int d = 0; d < 2; ++d) {
            const u32* vp = &v32s[(2 * p2 + d) * 68 + hwl2 * 17];
            #pragma unroll
            for (int jp = 0; jp < 16; ++jp)
                unpack2(vp[jp], vj[d][2*jp], vj[d][2*jp+1]);
        }
        float acc2[2][16];
        #pragma unroll
        for (int d = 0; d < 2; ++d)
            #pragma unroll
            for (int i = 0; i < 16; ++i) acc2[d][i] = 0.f;
        #pragma unroll 2
        for (int i = 0; i < 16; ++i) {
            const u32* Pr = &P32s[h * 576 + (ts + i) * 18];
            #pragma unroll
            for (int jp = 0; jp < 16; ++jp) {
                float p0, p1; unpack2(Pr[jp], p0, p1);
                acc2[0][i] = fmaf(p0, vj[0][2*jp], acc2[0][i]);
                acc2[0][i] = fmaf(p1, vj[0][2*jp+1], acc2[0][i]);
                acc2[1][i] = fmaf(p0, vj[1][2*jp], acc2[1][i]);
                acc2[1][i] = fmaf(p1, vj[1][2*jp+1], acc2[1][i]);
            }
        }
        #pragma unroll
        for (int d = 0; d < 2; ++d)
            #pragma unroll
            for (int i = 0; i < 16; ++i)
                uni[(2 * p2 + d) * 132 + hwl2 * 33 + ts + i] = acc2[d][i];
    }
    __syncthreads();
    // ---- phase 3: proj ----
    {
        int og = tid >> 6, lane = tid & 63;
        int tt = lane & 31, rep = lane >> 5;
        int ogu = __builtin_amdgcn_readfirstlane(og);
        const float* wpt = wpT + (size_t)b * 4096 + ogu * 16;
        float acc[16][2];
        #pragma unroll
        for (int oo = 0; oo < 16; ++oo) { acc[oo][0] = 0.f; acc[oo][1] = 0.f; }
        #pragma unroll 4
        for (int i = 0; i < 64; ++i) {
            float a0 = uni[i * 132 + (rep * 2) * 33 + tt];
            float a1 = uni[i * 132 + (rep * 2) * 33 + 33 + tt];
            const float* wr = wpt + i * 64;   // wave-uniform -> s_load
            #pragma unroll
            for (int oo = 0; oo < 16; ++oo) {
                acc[oo][0] = fmaf(wr[oo], a0, acc[oo][0]);
                acc[oo][1] = fmaf(wr[oo], a1, acc[oo][1]);
            }
        }
        float nz0 = pnoise[(size_t)b * PP + (size_t)(hw0 + rep * 2) * 32 + tt];
        float nz1 = pnoise[(size_t)b * PP + (size_t)(hw0 + rep * 2 + 1) * 32 + tt];
        #pragma unroll
        for (int oo = 0; oo < 16; ++oo) {
            int o = ogu * 16 + oo;
            float npv = pnp[o], bpv = pbp[o];
            size_t base = (size_t)(b * 64 + o) * PP + tt;
            out[base + (size_t)(hw0 + rep * 2) * 32]     = acc[oo][0] + npv * nz0 + bpv;
            out[base + (size_t)(hw0 + rep * 2 + 1) * 32] = acc[oo][1] + npv * nz1 + bpv;
        }
    }
}

// ---------------- sentinels ------------------------------------------------
__global__ __launch_bounds__(256) void k_zero(float* __restrict__ out, int n) {
    int i = blockIdx.x * 256 + threadIdx.x;
    if (i < n) out[i] = 0.f;
}
__global__ void k_code(float* __restrict__ out, float code) { out[0] = code; }

extern "C" void kernel_launch(void* const* d_in, const int* in_sizes, int n_in,
                              void* d_out, int out_size, void* d_ws, size_t ws_size,
                              hipStream_t stream) {
    float* out = (float*)d_out;
    const int exp_sizes[14] = {4*64*32768, 4*512, 192*64, 64*512, 64, 192, 192,
                               4*32768, 64*64, 64*512, 64, 64, 64, 4*32768};
    bool ok = (n_in == 14) && (out_size == 4*64*32768);
    if (ok) for (int k = 0; k < 14; ++k) ok = ok && (in_sizes[k] == exp_sizes[k]);
    if (!ok) {
        k_zero<<<(out_size + 255) / 256, 256, 0, stream>>>(out, out_size);
        k_code<<<1, 1, 0, stream>>>(out, 1000.f);
        return;
    }
    if (ws_size < 393216) {
        k_zero<<<(out_size + 255) / 256, 256, 0, stream>>>(out, out_size);
        k_code<<<1, 1, 0, stream>>>(out, 2000.f + (float)(ws_size >> 20));
        return;
    }
    char* ws = (char*)d_ws;
    float* S     = (float*)ws;               // 128 KB (4,8,32,32)
    float* wqkT  = (float*)(ws + 131072);    // 128 KB (4,64e,128o)
    float* wvT   = (float*)(ws + 262144);    //  64 KB (4,64e,64c)
    float* wpT   = (float*)(ws + 327680);    //  64 KB (4,64i,64o)

    k_prep   <<<1024, 64,  0, stream>>>((const float*)d_in[1], (const float*)d_in[3],
                                        (const float*)d_in[4], (const float*)d_in[9],
                                        (const float*)d_in[10], (const float*)d_in[2],
                                        (const float*)d_in[8], wqkT, wvT, wpT, S);
    k_fscores<<<1024, 256, 0, stream>>>((const float*)d_in[0], wqkT,
                                        (const float*)d_in[5], (const float*)d_in[6],
                                        (const float*)d_in[7], S);
    k_out    <<<1024, 256, 0, stream>>>((const float*)d_in[0], wvT,
                                        (const float*)d_in[5], (const float*)d_in[6],
                                        (const float*)d_in[7], S, wpT,
                                        (const float*)d_in[11], (const float*)d_in[12],
                                        (const float*)d_in[13], out);
    hipError_t e = hipGetLastError();
    if (e != hipSuccess) {
        k_zero<<<(out_size + 255) / 256, 256, 0, stream>>>(out, out_size);
        k_code<<<1, 1, 0, stream>>>(out, 3000.f + (float)e);
    }
}

// Round 8
// 206.897 us; speedup vs baseline: 1.1113x; 1.1113x over previous
//
#include <hip/hip_runtime.h>

typedef unsigned short u16;
typedef unsigned int   u32;

#define PP 32768          // H*W*T
#define CC 64

__device__ __forceinline__ u16 f2b(float f) {
    u32 u; __builtin_memcpy(&u, &f, 4);
    u32 r = (u + 0x7FFFu + ((u >> 16) & 1u)) >> 16;
    return (u16)r;
}
__device__ __forceinline__ void unpack2(u32 v, float& lo, float& hi) {
    u32 a = v << 16; u32 b = v & 0xFFFF0000u;
    __builtin_memcpy(&lo, &a, 4); __builtin_memcpy(&hi, &b, 4);
}
__device__ __forceinline__ u32 pack2(float lo, float hi) {
    return (u32)f2b(lo) | ((u32)f2b(hi) << 16);
}

// ---------------- K1: style dot, one output channel per block --------------
// grid 512 = b(4) x sel(2) x o(64); 64 thr; coalesced 2KB row read + shfl.
__global__ __launch_bounds__(64) void k_style2(
        const float* __restrict__ style, const float* __restrict__ qkv_lw,
        const float* __restrict__ qkv_lb, const float* __restrict__ proj_lw,
        const float* __restrict__ proj_lb, float* __restrict__ s_out) {
    int id = blockIdx.x;
    int b = id >> 7, sel = (id >> 6) & 1, o = id & 63;
    int t = threadIdx.x;
    const float* lw = sel ? proj_lw : qkv_lw;
    const float* lb = sel ? proj_lb : qkv_lb;
    const float* st = style + b * 512 + t * 8;
    const float* wr = lw + (size_t)o * 512 + t * 8;
    float4 s0 = *(const float4*)st, s1 = *(const float4*)(st + 4);
    float4 w0 = *(const float4*)wr, w1 = *(const float4*)(wr + 4);
    float p = s0.x*w0.x + s0.y*w0.y + s0.z*w0.z + s0.w*w0.w
            + s1.x*w1.x + s1.y*w1.y + s1.z*w1.z + s1.w*w1.w;
    #pragma unroll
    for (int off = 32; off > 0; off >>= 1) p += __shfl_xor(p, off, 64);
    if (t == 0) s_out[b * 128 + sel * 64 + o] = p + lb[o];
}

// ---------------- K2: normalized modulated weights + S zero ----------------
// wqkT[b][e][o<128]; wvT[b][e][c]; wpT[b][i][o]
__global__ __launch_bounds__(64) void k_wnorm(
        const float* __restrict__ qkv_w, const float* __restrict__ proj_w,
        const float* __restrict__ s, float* __restrict__ wqkT,
        float* __restrict__ wvT, float* __restrict__ wpT, float* __restrict__ S) {
    int id = blockIdx.x;           // 4 * 256
    int b = id >> 8, o = id & 255, i = threadIdx.x;
    if (i < 32) S[(size_t)id * 32 + i] = 0.f;     // 1024*32 = |S| exactly
    float wv;
    if (o < 192) wv = qkv_w[o * 64 + i] * s[b * 128 + i];
    else         wv = proj_w[(o - 192) * 64 + i] * s[b * 128 + 64 + i];
    float sq = wv * wv;
    #pragma unroll
    for (int off = 32; off > 0; off >>= 1) sq += __shfl_xor(sq, off, 64);
    float val = wv * rsqrtf(sq + 1e-8f);
    if (o < 128)      wqkT[((size_t)b * 64 + i) * 128 + o]        = val;
    else if (o < 192) wvT [((size_t)b * 64 + i) * 64 + (o - 128)] = val;
    else              wpT [((size_t)b * 64 + i) * 64 + (o - 192)] = val;
}

// ---------------- K3: fused q,k recompute + scores (r6-proven) -------------
// grid 1024 = b x n(8) x chunk(32 of 32hw); 64 KB LDS -> 2 blocks/CU.
__global__ __launch_bounds__(256) void k_fscores(
        const float* __restrict__ x, const float* __restrict__ wqkT,
        const float* __restrict__ qnp, const float* __restrict__ qbp,
        const float* __restrict__ qnoise, float* __restrict__ S) {
    int bidx = blockIdx.x;
    int b = bidx >> 8, n = (bidx >> 5) & 7, chunk = bidx & 31;
    int tid = threadIdx.x;
    __shared__ float q_lds[8192];     // [c<8][hw_l*32+t]
    __shared__ float k_lds[8192];
    float qa[8][4], ka[8][4];
    #pragma unroll
    for (int c = 0; c < 8; ++c)
        #pragma unroll
        for (int j = 0; j < 4; ++j) { qa[c][j] = 0.f; ka[c][j] = 0.f; }
    const float* xb = x + (size_t)b * CC * PP + chunk * 1024 + tid * 4;
    const float* wb = wqkT + (size_t)b * 8192 + n * 8;
    #pragma unroll 2
    for (int e = 0; e < 64; ++e) {
        float4 xv = *(const float4*)(xb + (size_t)e * PP);
        float xr[4] = {xv.x, xv.y, xv.z, xv.w};
        const float* wr = wb + e * 128;          // wave-uniform -> s_load
        #pragma unroll
        for (int c = 0; c < 8; ++c) {
            float wq_ = wr[c], wk_ = wr[64 + c];
            #pragma unroll
            for (int j = 0; j < 4; ++j) {
                qa[c][j] = fmaf(wq_, xr[j], qa[c][j]);
                ka[c][j] = fmaf(wk_, xr[j], ka[c][j]);
            }
        }
    }
    {
        float4 nz4 = *(const float4*)(qnoise + (size_t)b * PP + chunk * 1024 + tid * 4);
        float nz[4] = {nz4.x, nz4.y, nz4.z, nz4.w};
        #pragma unroll
        for (int c = 0; c < 8; ++c) {
            float qn = qnp[n * 8 + c], qb_ = qbp[n * 8 + c];
            float kn = qnp[64 + n * 8 + c], kb_ = qbp[64 + n * 8 + c];
            float4 qo, ko;
            qo.x = qa[c][0] + qn * nz[0] + qb_;  ko.x = ka[c][0] + kn * nz[0] + kb_;
            qo.y = qa[c][1] + qn * nz[1] + qb_;  ko.y = ka[c][1] + kn * nz[1] + kb_;
            qo.z = qa[c][2] + qn * nz[2] + qb_;  ko.z = ka[c][2] + kn * nz[2] + kb_;
            qo.w = qa[c][3] + qn * nz[3] + qb_;  ko.w = ka[c][3] + kn * nz[3] + kb_;
            *(float4*)&q_lds[c * 1024 + tid * 4] = qo;
            *(float4*)&k_lds[c * 1024 + tid * 4] = ko;
        }
    }
    __syncthreads();
    int wave = tid >> 6, lane = tid & 63;
    int ig = lane >> 3, jg = lane & 7;
    float acc[16];
    #pragma unroll
    for (int q = 0; q < 16; ++q) acc[q] = 0.f;
    #pragma unroll 4
    for (int i = 0; i < 64; ++i) {
        int e = wave * 64 + i, c = e >> 5, hl = e & 31;
        float4 qv = *(const float4*)&q_lds[c * 1024 + hl * 32 + ig * 4];
        float4 kv = *(const float4*)&k_lds[c * 1024 + hl * 32 + jg * 4];
        float qa4[4] = {qv.x, qv.y, qv.z, qv.w};
        float ka4[4] = {kv.x, kv.y, kv.z, kv.w};
        #pragma unroll
        for (int ii = 0; ii < 4; ++ii)
            #pragma unroll
            for (int jj = 0; jj < 4; ++jj)
                acc[ii * 4 + jj] = fmaf(qa4[ii], ka4[jj], acc[ii * 4 + jj]);
    }
    __syncthreads();                  // q_lds dead -> reduction scratch
    #pragma unroll
    for (int t = 0; t < 16; ++t) q_lds[t * 256 + tid] = acc[t];
    __syncthreads();
    if (wave == 0) {
        float* Sb = S + ((size_t)b * 8 + n) * 1024;
        #pragma unroll
        for (int t = 0; t < 16; ++t) {
            float s2 = q_lds[t * 256 + lane]       + q_lds[t * 256 + 64 + lane]
                     + q_lds[t * 256 + 128 + lane] + q_lds[t * 256 + 192 + lane];
            int ii = t >> 2, jj = t & 3;
            atomicAdd(&Sb[(ig * 4 + ii) * 32 + jg * 4 + jj], s2);
        }
    }
}

// ---------------- K4: softmax + v recompute + PV + proj --------------------
// grid 1024 = b x hwblk4; 256 thr; LDS ~72.7 KB -> 2 blocks/CU.
__global__ __launch_bounds__(256) void k_out(
        const float* __restrict__ x, const float* __restrict__ wvT,
        const float* __restrict__ qnp, const float* __restrict__ qbp,
        const float* __restrict__ qnoise, const float* __restrict__ Sg,
        const float* __restrict__ wpT, const float* __restrict__ pnp,
        const float* __restrict__ pbp, const float* __restrict__ pnoise,
        float* __restrict__ out) {
    int bidx = blockIdx.x;
    int b = bidx >> 8, hw0 = (bidx & 255) * 4;
    int tid = threadIdx.x;
    __shared__ u32   P32s[8 * 577];     // [h][t*18 + jp], stride 577: 2-way max
    __shared__ float uni[9216];         // ph1: xs[e][hwl*36+t]; ph2/3: As[i*132+hwl*33+t]
    __shared__ u32   v32s[64 * 68];     // [ich][hwl*17 + t/2] packed bf16 pairs
    // ---- fused softmax: thread = score row (n = tid>>5, i = tid&31) ----
    {
        int n = tid >> 5, i2 = tid & 31;
        const float* Srow = Sg + ((size_t)b * 8 + n) * 1024 + i2 * 32;
        float v[32];
        #pragma unroll
        for (int j4 = 0; j4 < 8; ++j4) {
            float4 s4 = *(const float4*)(Srow + j4 * 4);
            v[j4 * 4] = s4.x; v[j4 * 4 + 1] = s4.y;
            v[j4 * 4 + 2] = s4.z; v[j4 * 4 + 3] = s4.w;
        }
        float slope = exp2f(-(float)(n + 1));
        float m = -3e38f;
        #pragma unroll
        for (int j = 0; j < 32; ++j) {
            float val = v[j] * 0.011048543456039806f - slope * fabsf((float)(i2 - j));
            if (j <= i2) val = -1e18f;             // tril incl. diag masked
            v[j] = val; m = fmaxf(m, val);
        }
        float ssum = 0.f;
        #pragma unroll
        for (int j = 0; j < 32; ++j) { float e2 = expf(v[j] - m); v[j] = e2; ssum += e2; }
        float r = 1.f / ssum;
        #pragma unroll
        for (int jp = 0; jp < 16; ++jp)
            P32s[n * 577 + i2 * 18 + jp] = pack2(v[2 * jp] * r, v[2 * jp + 1] * r);
    }
    // ---- stage x: uni[e*144 + hwl*36 + t] ----
    const float* xb = x + (size_t)b * CC * PP + (size_t)hw0 * 32;
    #pragma unroll
    for (int r4 = 0; r4 < 8; ++r4) {
        int idx = r4 * 256 + tid;             // 0..2047 float4s
        int e = idx >> 5, rem = idx & 31, hwl = rem >> 3, tq = rem & 7;
        float4 xv = *(const float4*)(xb + (size_t)e * PP + rem * 4);
        *(float4*)&uni[e * 144 + hwl * 36 + tq * 4] = xv;
    }
    __syncthreads();
    // ---- phase 1: v = W x (4 vch x 8 t per thread) -> bf16 LDS ----
    {
        int ig = tid >> 4, r = tid & 15, hwl = r >> 2, th = r & 3, t0 = th * 8;
        float acc[4][8];
        #pragma unroll
        for (int ii = 0; ii < 4; ++ii)
            #pragma unroll
            for (int j = 0; j < 8; ++j) acc[ii][j] = 0.f;
        const float* wvb = wvT + (size_t)b * 4096 + ig * 4;
        #pragma unroll 2
        for (int e = 0; e < 64; ++e) {
            float4 w4 = *(const float4*)(wvb + e * 64);
            float wr[4] = {w4.x, w4.y, w4.z, w4.w};
            const float* xp = &uni[e * 144 + hwl * 36 + t0];
            float4 xa = *(const float4*)xp;
            float4 xc = *(const float4*)(xp + 4);
            float x8[8] = {xa.x, xa.y, xa.z, xa.w, xc.x, xc.y, xc.z, xc.w};
            #pragma unroll
            for (int ii = 0; ii < 4; ++ii)
                #pragma unroll
                for (int j = 0; j < 8; ++j)
                    acc[ii][j] = fmaf(wr[ii], x8[j], acc[ii][j]);
        }
        float4 np4 = *(const float4*)(qnp + 128 + ig * 4);
        float4 bp4 = *(const float4*)(qbp + 128 + ig * 4);
        float npr[4] = {np4.x, np4.y, np4.z, np4.w};
        float bpr[4] = {bp4.x, bp4.y, bp4.z, bp4.w};
        const float* nzp = qnoise + (size_t)b * PP + (size_t)(hw0 + hwl) * 32 + t0;
        float4 na = *(const float4*)nzp;
        float4 nc = *(const float4*)(nzp + 4);
        float nz[8] = {na.x, na.y, na.z, na.w, nc.x, nc.y, nc.z, nc.w};
        #pragma unroll
        for (int ii = 0; ii < 4; ++ii) {
            int ich = ig * 4 + ii;
            #pragma unroll
            for (int q = 0; q < 4; ++q) {
                float y0 = acc[ii][2*q]   + npr[ii] * nz[2*q]   + bpr[ii];
                float y1 = acc[ii][2*q+1] + npr[ii] * nz[2*q+1] + bpr[ii];
                v32s[ich * 68 + hwl * 17 + th * 4 + q] = pack2(y0, y1);
            }
        }
    }
    __syncthreads();   // v32s complete; uni (xs) dead -> becomes As
    // ---- phase 2: A[ich][hwl][t] = sum_j P[h][t][j] v[ich][hwl][j] ----
    {
        int p2 = tid >> 3, r3 = tid & 7, hwl2 = r3 >> 1, ts = (r3 & 1) * 16;
        int h = p2 >> 2;
        float vj[2][32];
        #pragma unroll
        for (int d = 0; d < 2; ++d) {
            const u32* vp = &v32s[(2 * p2 + d) * 68 + hwl2 * 17];
            #pragma unroll
            for (int jp = 0; jp < 16; ++jp)
                unpack2(vp[jp], vj[d][2*jp], vj[d][2*jp+1]);
        }
        float acc2[2][16];
        #pragma unroll
        for (int d = 0; d < 2; ++d)
            #pragma unroll
            for (int i = 0; i < 16; ++i) acc2[d][i] = 0.f;
        #pragma unroll 2
        for (int i = 0; i < 16; ++i) {
            const u32* Pr = &P32s[h * 577 + (ts + i) * 18];
            #pragma unroll
            for (int jp = 0; jp < 16; ++jp) {
                float p0, p1; unpack2(Pr[jp], p0, p1);
                acc2[0][i] = fmaf(p0, vj[0][2*jp], acc2[0][i]);
                acc2[0][i] = fmaf(p1, vj[0][2*jp+1], acc2[0][i]);
                acc2[1][i] = fmaf(p0, vj[1][2*jp], acc2[1][i]);
                acc2[1][i] = fmaf(p1, vj[1][2*jp+1], acc2[1][i]);
            }
        }
        #pragma unroll
        for (int d = 0; d < 2; ++d)
            #pragma unroll
            for (int i = 0; i < 16; ++i)
                uni[(2 * p2 + d) * 132 + hwl2 * 33 + ts + i] = acc2[d][i];
    }
    __syncthreads();
    // ---- phase 3: proj ----
    {
        int og = tid >> 6, lane = tid & 63;
        int tt = lane & 31, rep = lane >> 5;
        int ogu = __builtin_amdgcn_readfirstlane(og);
        const float* wpt = wpT + (size_t)b * 4096 + ogu * 16;
        float acc[16][2];
        #pragma unroll
        for (int oo = 0; oo < 16; ++oo) { acc[oo][0] = 0.f; acc[oo][1] = 0.f; }
        #pragma unroll 4
        for (int i = 0; i < 64; ++i) {
            float a0 = uni[i * 132 + (rep * 2) * 33 + tt];
            float a1 = uni[i * 132 + (rep * 2) * 33 + 33 + tt];
            const float* wr = wpt + i * 64;   // wave-uniform -> s_load
            #pragma unroll
            for (int oo = 0; oo < 16; ++oo) {
                acc[oo][0] = fmaf(wr[oo], a0, acc[oo][0]);
                acc[oo][1] = fmaf(wr[oo], a1, acc[oo][1]);
            }
        }
        float nz0 = pnoise[(size_t)b * PP + (size_t)(hw0 + rep * 2) * 32 + tt];
        float nz1 = pnoise[(size_t)b * PP + (size_t)(hw0 + rep * 2 + 1) * 32 + tt];
        #pragma unroll
        for (int oo = 0; oo < 16; ++oo) {
            int o = ogu * 16 + oo;
            float npv = pnp[o], bpv = pbp[o];
            size_t base = (size_t)(b * 64 + o) * PP + tt;
            out[base + (size_t)(hw0 + rep * 2) * 32]     = acc[oo][0] + npv * nz0 + bpv;
            out[base + (size_t)(hw0 + rep * 2 + 1) * 32] = acc[oo][1] + npv * nz1 + bpv;
        }
    }
}

// ---------------- sentinels ------------------------------------------------
__global__ __launch_bounds__(256) void k_zero(float* __restrict__ out, int n) {
    int i = blockIdx.x * 256 + threadIdx.x;
    if (i < n) out[i] = 0.f;
}
__global__ void k_code(float* __restrict__ out, float code) { out[0] = code; }

extern "C" void kernel_launch(void* const* d_in, const int* in_sizes, int n_in,
                              void* d_out, int out_size, void* d_ws, size_t ws_size,
                              hipStream_t stream) {
    float* out = (float*)d_out;
    const int exp_sizes[14] = {4*64*32768, 4*512, 192*64, 64*512, 64, 192, 192,
                               4*32768, 64*64, 64*512, 64, 64, 64, 4*32768};
    bool ok = (n_in == 14) && (out_size == 4*64*32768);
    if (ok) for (int k = 0; k < 14; ++k) ok = ok && (in_sizes[k] == exp_sizes[k]);
    if (!ok) {
        k_zero<<<(out_size + 255) / 256, 256, 0, stream>>>(out, out_size);
        k_code<<<1, 1, 0, stream>>>(out, 1000.f);
        return;
    }
    if (ws_size < 395264) {
        k_zero<<<(out_size + 255) / 256, 256, 0, stream>>>(out, out_size);
        k_code<<<1, 1, 0, stream>>>(out, 2000.f + (float)(ws_size >> 20));
        return;
    }
    char* ws = (char*)d_ws;
    float* S     = (float*)ws;               // 128 KB (4,8,32,32)
    float* wqkT  = (float*)(ws + 131072);    // 128 KB (4,64e,128o)
    float* wvT   = (float*)(ws + 262144);    //  64 KB (4,64e,64c)
    float* wpT   = (float*)(ws + 327680);    //  64 KB (4,64i,64o)
    float* s_sty = (float*)(ws + 393216);    //   2 KB (4,128)

    k_style2 <<<512,  64,  0, stream>>>((const float*)d_in[1], (const float*)d_in[3],
                                        (const float*)d_in[4], (const float*)d_in[9],
                                        (const float*)d_in[10], s_sty);
    k_wnorm  <<<1024, 64,  0, stream>>>((const float*)d_in[2], (const float*)d_in[8],
                                        s_sty, wqkT, wvT, wpT, S);
    k_fscores<<<1024, 256, 0, stream>>>((const float*)d_in[0], wqkT,
                                        (const float*)d_in[5], (const float*)d_in[6],
                                        (const float*)d_in[7], S);
    k_out    <<<1024, 256, 0, stream>>>((const float*)d_in[0], wvT,
                                        (const float*)d_in[5], (const float*)d_in[6],
                                        (const float*)d_in[7], S, wpT,
                                        (const float*)d_in[11], (const float*)d_in[12],
                                        (const float*)d_in[13], out);
    hipError_t e = hipGetLastError();
    if (e != hipSuccess) {
        k_zero<<<(out_size + 255) / 256, 256, 0, stream>>>(out, out_size);
        k_code<<<1, 1, 0, stream>>>(out, 3000.f + (float)e);
    }
}